// Round 18
// baseline (186.296 us; speedup 1.0000x reference)
//
#include <hip/hip_runtime.h>

#define L_SEQ 2048
#define NH    16
#define HD    64
#define HDIM  1024

typedef __attribute__((ext_vector_type(8))) short  short8;
typedef __attribute__((ext_vector_type(4))) float  f32x4;

__device__ __forceinline__ unsigned short f2bf(float f) {
    unsigned int u = __float_as_uint(f);
    u += 0x7fffu + ((u >> 16) & 1u);
    return (unsigned short)(u >> 16);
}

__device__ __forceinline__ short8 ld8(const unsigned short* p) {
    return *(const short8*)p;
}

// HW packed f32->bf16 (RNE): dst = {lo: bf16(a), hi: bf16(b)}
__device__ __forceinline__ unsigned int cvtpk(float a, float b) {
    unsigned int r;
    asm("v_cvt_pk_bf16_f32 %0, %1, %2" : "=v"(r) : "v"(a), "v"(b));
    return r;
}

// async global->LDS, 16 bytes per lane (dest = wave-uniform base + lane*16)
__device__ __forceinline__ void gl16(const unsigned short* g, unsigned short* l) {
    __builtin_amdgcn_global_load_lds(
        (const __attribute__((address_space(1))) void*)g,
        (__attribute__((address_space(3))) void*)l, 16, 0, 0);
}

// ---- merged fp32 -> bf16 conversion: q, k, v, Wq..Wo, pe in one launch ----
__global__ __launch_bounds__(256) void cvt_a_kernel(
    const float* __restrict__ q, const float* __restrict__ k, const float* __restrict__ v,
    const float* __restrict__ Wq, const float* __restrict__ Wk,
    const float* __restrict__ Wv, const float* __restrict__ Wo,
    const float* __restrict__ pe,
    unsigned short* __restrict__ S1, unsigned short* __restrict__ Vb,
    unsigned short* __restrict__ VSCR,
    unsigned short* __restrict__ D, unsigned short* __restrict__ E)
{
    const int y = blockIdx.y;
    const float* src; unsigned short* dst; int n8;
    switch (y) {
        case 0:  src = q;  dst = S1;            n8 = 524288; break;
        case 1:  src = k;  dst = Vb;            n8 = 524288; break;
        case 2:  src = Wq; dst = D;             n8 = 131072; break;
        case 3:  src = Wk; dst = D + 1048576;   n8 = 131072; break;
        case 4:  src = Wv; dst = D + 2097152;   n8 = 131072; break;
        case 5:  src = Wo; dst = D + 3145728;   n8 = 131072; break;
        case 6:  src = pe; dst = E;             n8 = 32760;  break;
        default: src = v;  dst = VSCR;          n8 = 524288; break;
    }
    const int i = blockIdx.x * 256 + threadIdx.x;
    if (i >= n8) return;
    const float4 a = ((const float4*)src)[2 * i];
    const float4 b = ((const float4*)src)[2 * i + 1];
    union { short8 v; unsigned int u[4]; } o;
    o.u[0] = cvtpk(a.x, a.y); o.u[1] = cvtpk(a.z, a.w);
    o.u[2] = cvtpk(b.x, b.y); o.u[3] = cvtpk(b.z, b.w);
    ((short8*)dst)[i] = o.v;
}

// ---- bf16 128x128 tile GEMM core (m97-style): Y = X * W^T ----
__device__ __forceinline__ void gemm_bf16_core(
    const unsigned short* __restrict__ Xb,
    const unsigned short* __restrict__ Wb,
    int row0, int col0,
    unsigned short* As, unsigned short* Bs,
    f32x4 (&acc)[4][4])
{
    const int t    = threadIdx.x;
    const int lane = t & 63;
    const int wid  = t >> 6;
    const int lr   = lane & 15;
    const int lg   = lane >> 4;
    const int wr   = (wid >> 1) << 6;
    const int wc   = (wid & 1) << 6;

    const int grow = lane >> 3;
    const int gcol = ((lane & 7) ^ grow) << 3;

#pragma unroll
    for (int m = 0; m < 4; ++m)
#pragma unroll
        for (int n = 0; n < 4; ++n)
            acc[m][n] = (f32x4)0.0f;

    const unsigned short* xs = Xb + (size_t)(row0 + grow) * 1024 + gcol;
    const unsigned short* ws = Wb + (size_t)(col0 + grow) * 1024 + gcol;

    for (int k0 = 0; k0 < 1024; k0 += 64) {
        __syncthreads();
#pragma unroll
        for (int i = 0; i < 4; ++i) {
            const int seg = (i << 2) + wid;
            gl16(xs + (size_t)(seg << 3) * 1024 + k0, As + seg * 512);
            gl16(ws + (size_t)(seg << 3) * 1024 + k0, Bs + seg * 512);
        }
        __syncthreads();

        short8 af[4][2], bf[4][2];
#pragma unroll
        for (int m = 0; m < 4; ++m) {
            const int row = wr + (m << 4) + lr;
#pragma unroll
            for (int h = 0; h < 2; ++h)
                af[m][h] = ld8(&As[row * 64 + ((((h << 2) + lg) ^ (lr & 7)) << 3)]);
        }
#pragma unroll
        for (int n = 0; n < 4; ++n) {
            const int row = wc + (n << 4) + lr;
#pragma unroll
            for (int h = 0; h < 2; ++h)
                bf[n][h] = ld8(&Bs[row * 64 + ((((h << 2) + lg) ^ (lr & 7)) << 3)]);
        }
#pragma unroll
        for (int m = 0; m < 4; ++m)
#pragma unroll
            for (int n = 0; n < 4; ++n) {
                acc[m][n] = __builtin_amdgcn_mfma_f32_16x16x32_bf16(af[m][0], bf[n][0], acc[m][n], 0, 0, 0);
                acc[m][n] = __builtin_amdgcn_mfma_f32_16x16x32_bf16(af[m][1], bf[n][1], acc[m][n], 0, 0, 0);
            }
    }
}

// q+k+v projections in ONE launch: z = blk>>8 (0=q scaled by log2e/8, 1=k,
// both -> (b,h,L,d); 2 = v -> transposed (b,h,d,L)).
__global__ __launch_bounds__(256) void proj_qkv_kernel(
    const unsigned short* __restrict__ Xq, const unsigned short* __restrict__ Xk,
    const unsigned short* __restrict__ Xv, const unsigned short* __restrict__ D,
    const float* __restrict__ bq, const float* __restrict__ bk, const float* __restrict__ bv,
    unsigned short* __restrict__ Qb, unsigned short* __restrict__ Kb,
    unsigned short* __restrict__ VT)
{
    __shared__ __align__(16) unsigned short As[128 * 64];
    __shared__ __align__(16) unsigned short Bs[128 * 64];

    const int z = blockIdx.x >> 8;
    const int d = blockIdx.x & 255;
    const int y = ((d >> 6) << 3) | (d & 7);
    const int x = (d >> 3) & 7;
    const int row0 = y << 7, col0 = x << 7;

    const unsigned short* Xb = (z == 0) ? Xq : (z == 1) ? Xk : Xv;
    const unsigned short* Wb = D + (size_t)z * 1048576;
    const float* bias = (z == 0) ? bq : (z == 1) ? bk : bv;

    f32x4 acc[4][4];
    gemm_bf16_core(Xb, Wb, row0, col0, As, Bs, acc);

    const int t = threadIdx.x;
    const int lane = t & 63;
    const int wid  = t >> 6;
    const int lr = lane & 15, lg = lane >> 4;
    const int wr = (wid >> 1) << 6, wc = (wid & 1) << 6;

    if (z <= 1) {
        // log2e folded into q so softmax can use exp2 (bias inherits it since
        // the reference biases with the scaled q).
        const float scale = (z == 0) ? 0.125f * 1.44269504088896340736f : 1.0f;
        unsigned short* out = (z == 0) ? Qb : Kb;
#pragma unroll
        for (int n = 0; n < 4; ++n) {
            const int o = col0 + wc + (n << 4) + lr;
            const float bo = bias[o];
            const int h = o >> 6, dd = o & 63;
#pragma unroll
            for (int m = 0; m < 4; ++m) {
                const int ib = row0 + wr + (m << 4) + (lg << 2);
#pragma unroll
                for (int r = 0; r < 4; ++r) {
                    const int i = ib + r;
                    out[(((size_t)((i >> 11) * NH + h)) * L_SEQ + (i & (L_SEQ - 1))) * HD + dd] =
                        f2bf((acc[m][n][r] + bo) * scale);
                }
            }
        }
    } else {
#pragma unroll
        for (int n = 0; n < 4; ++n) {
            const int o = col0 + wc + (n << 4) + lr;
            const float bo = bias[o];
            const int h = o >> 6, dd = o & 63;
#pragma unroll
            for (int m = 0; m < 4; ++m) {
                const int ib = row0 + wr + (m << 4) + (lg << 2);
                const int b = ib >> 11, il = ib & (L_SEQ - 1);
                ushort4 pk;
                pk.x = f2bf(acc[m][n][0] + bo);
                pk.y = f2bf(acc[m][n][1] + bo);
                pk.z = f2bf(acc[m][n][2] + bo);
                pk.w = f2bf(acc[m][n][3] + bo);
                *(ushort4*)&VT[(((size_t)(b * NH + h)) * HD + dd) * L_SEQ + il] = pk;
            }
        }
    }
}

__global__ __launch_bounds__(256) void outproj_kernel(
    const unsigned short* __restrict__ Ob, const unsigned short* __restrict__ Wb,
    const float* __restrict__ bias, float* __restrict__ Yout)
{
    __shared__ __align__(16) unsigned short As[128 * 64];
    __shared__ __align__(16) unsigned short Bs[128 * 64];

    const int d = blockIdx.x;
    const int y = ((d >> 6) << 3) | (d & 7);
    const int x = (d >> 3) & 7;
    const int row0 = y << 7, col0 = x << 7;

    f32x4 acc[4][4];
    gemm_bf16_core(Ob, Wb, row0, col0, As, Bs, acc);

    const int t = threadIdx.x;
    const int lane = t & 63;
    const int wid  = t >> 6;
    const int lr = lane & 15, lg = lane >> 4;
    const int wr = (wid >> 1) << 6, wc = (wid & 1) << 6;

#pragma unroll
    for (int n = 0; n < 4; ++n) {
        const int o = col0 + wc + (n << 4) + lr;
        const float bo = bias[o];
#pragma unroll
        for (int m = 0; m < 4; ++m) {
            const int ib = row0 + wr + (m << 4) + (lg << 2);
#pragma unroll
            for (int r = 0; r < 4; ++r)
                Yout[(size_t)(ib + r) * HDIM + o] = acc[m][n][r] + bo;
        }
    }
}

// stage one 64x64 bf16 K and V tile into LDS via global_load_lds:
// linear LDS dest, inverse-swizzled global source (read side XORs chunk^row&7)
__device__ __forceinline__ void stage_kv(
    const unsigned short* __restrict__ kbase, const unsigned short* __restrict__ vbase,
    int j0, unsigned short (*Ksb)[64], unsigned short (*Vsb)[64], int wid, int lane)
{
    const int r8 = lane >> 3;
    const int gc = ((lane & 7) ^ r8) << 3;
#pragma unroll
    for (int s = 0; s < 2; ++s) {
        const int rw = (wid << 4) + (s << 3);
        gl16(kbase + (size_t)(j0 + rw + r8) * HD + gc, &Ksb[rw][0]);
        gl16(vbase + (size_t)(rw + r8) * L_SEQ + j0 + gc, &Vsb[rw][0]);
    }
}

// Flash attention, causal, skewed relative positional bias (transposed-S).
// 4 waves x 16 q-rows; K/V via global_load_lds double-buffer; exp2 softmax;
// wave-uniform mask skip; defer-max (THR=8).
// R18 changes vs proven R12: (1) skew buffer TRANSPOSED -> bldsT[qw][kr],
// stride 72: write conflicts 8-way -> <=4-way, gather 16x b32 -> 4x b128;
// (2) next tile's PE fragments loaded at loop top (pure loads, consumed next
// iteration after the barrier's vmcnt(0) has drained them).
__global__ __launch_bounds__(256, 3) void attn_kernel(
    const unsigned short* __restrict__ Q,
    const unsigned short* __restrict__ Kt,
    const unsigned short* __restrict__ VT,
    const unsigned short* __restrict__ PE,
    unsigned short* __restrict__ O)
{
    __shared__ __align__(16) unsigned short Ks[2][64][64];
    __shared__ __align__(16) unsigned short Vs[2][64][64];
    __shared__ __align__(16) float bldsT_all[4][16][72];

    const int t    = threadIdx.x;
    const int wid  = t >> 6;
    const int lane = t & 63;
    const int lr   = lane & 15;      // qr
    const int lg   = lane >> 4;
    const int lk   = lg << 3;

    const int p   = blockIdx.x;           // 0..1023
    const int bh  = p & 31;               // XCD = p%8 -> 4 bh per XCD
    const int rb  = 31 - (p >> 5);        // LPT: longest first
    const int i0  = rb << 6;
    const int i0w = i0 + (wid << 4);
    const int nt  = rb + 1;

    const unsigned short* kbase = Kt + (size_t)bh * L_SEQ * HD;
    const unsigned short* vbase = VT + (size_t)bh * HD * L_SEQ;

    float (*bldsT)[72] = bldsT_all[wid];

    const unsigned short* qb = Q + ((size_t)bh * L_SEQ + i0w + lr) * HD + lk;
    const short8 aq0 = ld8(qb);
    const short8 aq1 = ld8(qb + 32);

    const int gi    = i0w + lr;
    const int idx0  = ((lg & 1) << 7) + (lr << 2);   // byte index for ds_bpermute
    const int idx1  = idx0 + 64;
    const int selhi = lg >> 1;

    f32x4 oacc[4];
#pragma unroll
    for (int dt = 0; dt < 4; ++dt) oacc[dt] = (f32x4)0.0f;
    float mrun = -__builtin_inff();
    float lrun = 0.0f;

    // prologue: pqc (pt=0 tile of iteration 0) + PE fragments for pt=1..4
    f32x4 pqc = (f32x4)0.0f;
    short8 pe_c[4][2];
    {
        const int m0 = 2032 - i0w;        // mlo of tile 0
        const unsigned short* pp = PE + (size_t)(m0 + lr) * HD + lk;
        pqc = __builtin_amdgcn_mfma_f32_16x16x32_bf16(aq0, ld8(pp), pqc, 0, 0, 0);
        pqc = __builtin_amdgcn_mfma_f32_16x16x32_bf16(aq1, ld8(pp + 32), pqc, 0, 0, 0);
#pragma unroll
        for (int pt = 1; pt < 5; ++pt) {
            const unsigned short* pq_p = PE + (size_t)(m0 + (pt << 4) + lr) * HD + lk;
            pe_c[pt - 1][0] = ld8(pq_p);
            pe_c[pt - 1][1] = ld8(pq_p + 32);
        }
    }

    // prologue: stage tile 0 into buffer 0
    stage_kv(kbase, vbase, 0, Ks[0], Vs[0], wid, lane);
    __syncthreads();

    int cur = 0;
    for (int tt = 0; tt < nt; ++tt) {
        const int j0   = tt << 6;
        const bool more = (tt + 1 < nt);

        if (more)
            stage_kv(kbase, vbase, j0 + 64, Ks[cur ^ 1], Vs[cur ^ 1], wid, lane);

        // prefetch NEXT tile's PE fragments: pure loads, no consumer this
        // iteration; drained (at latest) by the barrier's vmcnt(0).
        short8 pe_n[4][2];
        if (more) {
            const int mlon = 2032 + j0 + 64 - i0w;
#pragma unroll
            for (int pt = 1; pt < 5; ++pt) {
                const unsigned short* pp = PE + (size_t)(mlon + (pt << 4) + lr) * HD + lk;
                pe_n[pt - 1][0] = ld8(pp);
                pe_n[pt - 1][1] = ld8(pp + 32);
            }
        }

        // ---- QK^T (transposed): K frags from swizzled LDS ----
        f32x4 s2[4];
#pragma unroll
        for (int ct = 0; ct < 4; ++ct) {
            const int row = (ct << 4) + lr;
            const short8 k0 = *(const short8*)&Ks[cur][row][(lg ^ (lr & 7)) << 3];
            const short8 k1 = *(const short8*)&Ks[cur][row][((4 + lg) ^ (lr & 7)) << 3];
            f32x4 a = (f32x4)0.0f;
            a = __builtin_amdgcn_mfma_f32_16x16x32_bf16(k0, aq0, a, 0, 0, 0);
            a = __builtin_amdgcn_mfma_f32_16x16x32_bf16(k1, aq1, a, 0, 0, 0);
            s2[ct] = a;
        }

        // ---- relative positional bias: MFMAs on PREFETCHED fragments ----
        f32x4 pq[5];
        pq[0] = pqc;
#pragma unroll
        for (int pt = 1; pt < 5; ++pt) {
            f32x4 a = (f32x4)0.0f;
            a = __builtin_amdgcn_mfma_f32_16x16x32_bf16(aq0, pe_c[pt - 1][0], a, 0, 0, 0);
            a = __builtin_amdgcn_mfma_f32_16x16x32_bf16(aq1, pe_c[pt - 1][1], a, 0, 0, 0);
            pq[pt] = a;
        }
        pqc = pq[4];

        // scatter Pq with skew folded in (TRANSPOSED): bldsT[qw][kr]
#pragma unroll
        for (int r = 0; r < 4; ++r) {
            const int qw = (lg << 2) + r;
            {
                const int kr = lr + qw - 15;
                if (kr >= 0) bldsT[qw][kr] = pq[0][r];
            }
#pragma unroll
            for (int pt = 1; pt < 4; ++pt)
                bldsT[qw][(pt << 4) + lr + qw - 15] = pq[pt][r];
            {
                const int kr = 49 + lr + qw;
                if (kr < 64) bldsT[qw][kr] = pq[4][r];
            }
        }

        // bias add via contiguous b128 gather; causal mask on diagonal tiles
        if (j0 + 63 > i0w) {
#pragma unroll
            for (int ct = 0; ct < 4; ++ct) {
                const float4 bv = *(const float4*)&bldsT[lr][(ct << 4) + (lg << 2)];
#pragma unroll
                for (int r = 0; r < 4; ++r) {
                    const int krl = (ct << 4) + (lg << 2) + r;
                    const float v = s2[ct][r] + ((const float*)&bv)[r];
                    s2[ct][r] = (j0 + krl > gi) ? -__builtin_inff() : v;
                }
            }
        } else {
#pragma unroll
            for (int ct = 0; ct < 4; ++ct) {
                const float4 bv = *(const float4*)&bldsT[lr][(ct << 4) + (lg << 2)];
#pragma unroll
                for (int r = 0; r < 4; ++r)
                    s2[ct][r] += ((const float*)&bv)[r];
            }
        }

        // online softmax (exp2 domain): per-lane row; tree + 2 shuffles
        float c0 = fmaxf(fmaxf(s2[0][0], s2[0][1]), fmaxf(s2[0][2], s2[0][3]));
        float c1 = fmaxf(fmaxf(s2[1][0], s2[1][1]), fmaxf(s2[1][2], s2[1][3]));
        float c2 = fmaxf(fmaxf(s2[2][0], s2[2][1]), fmaxf(s2[2][2], s2[2][3]));
        float c3 = fmaxf(fmaxf(s2[3][0], s2[3][1]), fmaxf(s2[3][2], s2[3][3]));
        float vmax = fmaxf(fmaxf(c0, c1), fmaxf(c2, c3));
        vmax = fmaxf(vmax, __shfl_xor(vmax, 16));
        vmax = fmaxf(vmax, __shfl_xor(vmax, 32));
        // defer-max (T13): skip rescale unless some row's max grew > 8
        if (!__all(vmax <= mrun + 8.0f)) {
            const float mnew = fmaxf(mrun, vmax);
            const float sc = __builtin_amdgcn_exp2f(mrun - mnew);
            mrun = mnew;
            lrun *= sc;
#pragma unroll
            for (int dt = 0; dt < 4; ++dt)
#pragma unroll
                for (int r = 0; r < 4; ++r)
                    oacc[dt][r] *= sc;
        }
#pragma unroll
        for (int ct = 0; ct < 4; ++ct)
#pragma unroll
            for (int r = 0; r < 4; ++r)
                s2[ct][r] = __builtin_amdgcn_exp2f(s2[ct][r] - mrun);
        float t0 = (s2[0][0] + s2[0][1]) + (s2[0][2] + s2[0][3]);
        float t1 = (s2[1][0] + s2[1][1]) + (s2[1][2] + s2[1][3]);
        float t2 = (s2[2][0] + s2[2][1]) + (s2[2][2] + s2[2][3]);
        float t3 = (s2[3][0] + s2[3][1]) + (s2[3][2] + s2[3][3]);
        float sum = (t0 + t1) + (t2 + t3);
        sum += __shfl_xor(sum, 16);
        sum += __shfl_xor(sum, 32);
        lrun += sum;

        // P -> bf16 B-fragments via cvt_pk + ds_bpermute (proven path)
        unsigned int pkl[4], pkh[4];
#pragma unroll
        for (int ct = 0; ct < 4; ++ct) {
            pkl[ct] = cvtpk(s2[ct][0], s2[ct][1]);
            pkh[ct] = cvtpk(s2[ct][2], s2[ct][3]);
        }
        union { short8 v; int u[4]; } pf0, pf1;
#pragma unroll
        for (int m = 0; m < 4; ++m) {
            const int bidx = (m & 2) ? idx1 : idx0;
            const int a0 = __builtin_amdgcn_ds_bpermute(bidx, (int)((m & 1) ? pkh[0] : pkl[0]));
            const int a1 = __builtin_amdgcn_ds_bpermute(bidx, (int)((m & 1) ? pkh[1] : pkl[1]));
            pf0.u[m] = selhi ? a1 : a0;
            const int b0 = __builtin_amdgcn_ds_bpermute(bidx, (int)((m & 1) ? pkh[2] : pkl[2]));
            const int b1 = __builtin_amdgcn_ds_bpermute(bidx, (int)((m & 1) ? pkh[3] : pkl[3]));
            pf1.u[m] = selhi ? b1 : b0;
        }

        // PV: V frags from swizzled LDS (16x16x32, proven)
#pragma unroll
        for (int dt = 0; dt < 4; ++dt) {
            const int row = (dt << 4) + lr;
            const short8 v0 = *(const short8*)&Vs[cur][row][(lg ^ (lr & 7)) << 3];
            const short8 v1 = *(const short8*)&Vs[cur][row][((4 + lg) ^ (lr & 7)) << 3];
            oacc[dt] = __builtin_amdgcn_mfma_f32_16x16x32_bf16(v0, pf0.v, oacc[dt], 0, 0, 0);
            oacc[dt] = __builtin_amdgcn_mfma_f32_16x16x32_bf16(v1, pf1.v, oacc[dt], 0, 0, 0);
        }

        // rotate prefetched PE fragments into place for the next iteration
        if (more) {
#pragma unroll
            for (int pt = 0; pt < 4; ++pt) {
                pe_c[pt][0] = pe_n[pt][0];
                pe_c[pt][1] = pe_n[pt][1];
            }
        }

        __syncthreads();
        cur ^= 1;
    }

    // epilogue: normalize, convert to bf16, store 8B per dt
    const float inv = 1.0f / lrun;
    const int b = bh >> 4, h = bh & 15;
#pragma unroll
    for (int dt = 0; dt < 4; ++dt) {
        uint2 u;
        u.x = cvtpk(oacc[dt][0] * inv, oacc[dt][1] * inv);
        u.y = cvtpk(oacc[dt][2] * inv, oacc[dt][3] * inv);
        *(uint2*)&O[((size_t)b * L_SEQ + i0w + lr) * HDIM + (h << 6) + (dt << 4) + (lg << 2)] = u;
    }
}

extern "C" void kernel_launch(void* const* d_in, const int* in_sizes, int n_in,
                              void* d_out, int out_size, void* d_ws, size_t ws_size,
                              hipStream_t stream) {
    (void)in_sizes; (void)n_in; (void)out_size;

    const float* query   = (const float*)d_in[0];
    const float* key_    = (const float*)d_in[1];
    const float* value   = (const float*)d_in[2];
    const float* Wq_w    = (const float*)d_in[3];
    const float* Wq_b    = (const float*)d_in[4];
    const float* Wk_w    = (const float*)d_in[5];
    const float* Wk_b    = (const float*)d_in[6];
    const float* Wv_w    = (const float*)d_in[7];
    const float* Wv_b    = (const float*)d_in[8];
    const float* Wo_w    = (const float*)d_in[9];
    const float* Wo_b    = (const float*)d_in[10];
    const float* pos_emb = (const float*)d_in[11];

    char* ws = (char*)d_ws;
    const size_t MB = 1024 * 1024;
    unsigned short* S1 = (unsigned short*)(ws);                 // 8 MB: q_bf16, later O_bf16
    unsigned short* Qb = (unsigned short*)(ws + 8  * MB);       // 8 MB
    unsigned short* Kb = (unsigned short*)(ws + 16 * MB);       // 8 MB
    unsigned short* Vb = (unsigned short*)(ws + 24 * MB);       // 8 MB: k_bf16
    unsigned short* D  = (unsigned short*)(ws + 32 * MB);       // 8 MB: Wq|Wk|Wv|Wo bf16
    unsigned short* E  = (unsigned short*)(ws + 40 * MB);       // 512 KB pe bf16

    // d_out (16.78 MB) doubles as scratch before the final overwrite:
    // half 0 = v_bf16 input, half 1 = vT (b,h,d,L)
    unsigned short* VSCR = (unsigned short*)d_out;
    unsigned short* VT   = VSCR + 4194304;

    const int npe = (2 * L_SEQ - 1) * HD;
    if (ws_size < (size_t)40 * MB + (size_t)npe * 2) return;

    cvt_a_kernel<<<dim3(2048, 8), 256, 0, stream>>>(query, key_, value,
                                                    Wq_w, Wk_w, Wv_w, Wo_w, pos_emb,
                                                    S1, Vb, VSCR, D, E);
    proj_qkv_kernel<<<768, 256, 0, stream>>>(S1, Vb, VSCR, D, Wq_b, Wk_b, Wv_b,
                                             Qb, Kb, VT);
    attn_kernel<<<1024, 256, 0, stream>>>(Qb, Kb, VT, E, S1);
    outproj_kernel<<<256, 256, 0, stream>>>(S1, D + 3145728, Wo_b, (float*)d_out);
}

// Round 19
// 171.855 us; speedup vs baseline: 1.0840x; 1.0840x over previous
//
#include <hip/hip_runtime.h>

#define L_SEQ 2048
#define NH    16
#define HD    64
#define HDIM  1024

typedef __attribute__((ext_vector_type(8))) short  short8;
typedef __attribute__((ext_vector_type(4))) float  f32x4;

__device__ __forceinline__ unsigned short f2bf(float f) {
    unsigned int u = __float_as_uint(f);
    u += 0x7fffu + ((u >> 16) & 1u);
    return (unsigned short)(u >> 16);
}

__device__ __forceinline__ short8 ld8(const unsigned short* p) {
    return *(const short8*)p;
}

// HW packed f32->bf16 (RNE): dst = {lo: bf16(a), hi: bf16(b)}
__device__ __forceinline__ unsigned int cvtpk(float a, float b) {
    unsigned int r;
    asm("v_cvt_pk_bf16_f32 %0, %1, %2" : "=v"(r) : "v"(a), "v"(b));
    return r;
}

// async global->LDS, 16 bytes per lane (dest = wave-uniform base + lane*16)
__device__ __forceinline__ void gl16(const unsigned short* g, unsigned short* l) {
    __builtin_amdgcn_global_load_lds(
        (const __attribute__((address_space(1))) void*)g,
        (__attribute__((address_space(3))) void*)l, 16, 0, 0);
}

// ---- merged fp32 -> bf16 conversion: q, k, v, Wq..Wo, pe in one launch ----
__global__ __launch_bounds__(256) void cvt_a_kernel(
    const float* __restrict__ q, const float* __restrict__ k, const float* __restrict__ v,
    const float* __restrict__ Wq, const float* __restrict__ Wk,
    const float* __restrict__ Wv, const float* __restrict__ Wo,
    const float* __restrict__ pe,
    unsigned short* __restrict__ S1, unsigned short* __restrict__ Vb,
    unsigned short* __restrict__ VSCR,
    unsigned short* __restrict__ D, unsigned short* __restrict__ E)
{
    const int y = blockIdx.y;
    const float* src; unsigned short* dst; int n8;
    switch (y) {
        case 0:  src = q;  dst = S1;            n8 = 524288; break;
        case 1:  src = k;  dst = Vb;            n8 = 524288; break;
        case 2:  src = Wq; dst = D;             n8 = 131072; break;
        case 3:  src = Wk; dst = D + 1048576;   n8 = 131072; break;
        case 4:  src = Wv; dst = D + 2097152;   n8 = 131072; break;
        case 5:  src = Wo; dst = D + 3145728;   n8 = 131072; break;
        case 6:  src = pe; dst = E;             n8 = 32760;  break;
        default: src = v;  dst = VSCR;          n8 = 524288; break;
    }
    const int i = blockIdx.x * 256 + threadIdx.x;
    if (i >= n8) return;
    const float4 a = ((const float4*)src)[2 * i];
    const float4 b = ((const float4*)src)[2 * i + 1];
    union { short8 v; unsigned int u[4]; } o;
    o.u[0] = cvtpk(a.x, a.y); o.u[1] = cvtpk(a.z, a.w);
    o.u[2] = cvtpk(b.x, b.y); o.u[3] = cvtpk(b.z, b.w);
    ((short8*)dst)[i] = o.v;
}

// ---- bf16 128x128 tile GEMM core (m97-style): Y = X * W^T ----
__device__ __forceinline__ void gemm_bf16_core(
    const unsigned short* __restrict__ Xb,
    const unsigned short* __restrict__ Wb,
    int row0, int col0,
    unsigned short* As, unsigned short* Bs,
    f32x4 (&acc)[4][4])
{
    const int t    = threadIdx.x;
    const int lane = t & 63;
    const int wid  = t >> 6;
    const int lr   = lane & 15;
    const int lg   = lane >> 4;
    const int wr   = (wid >> 1) << 6;
    const int wc   = (wid & 1) << 6;

    const int grow = lane >> 3;
    const int gcol = ((lane & 7) ^ grow) << 3;

#pragma unroll
    for (int m = 0; m < 4; ++m)
#pragma unroll
        for (int n = 0; n < 4; ++n)
            acc[m][n] = (f32x4)0.0f;

    const unsigned short* xs = Xb + (size_t)(row0 + grow) * 1024 + gcol;
    const unsigned short* ws = Wb + (size_t)(col0 + grow) * 1024 + gcol;

    for (int k0 = 0; k0 < 1024; k0 += 64) {
        __syncthreads();
#pragma unroll
        for (int i = 0; i < 4; ++i) {
            const int seg = (i << 2) + wid;
            gl16(xs + (size_t)(seg << 3) * 1024 + k0, As + seg * 512);
            gl16(ws + (size_t)(seg << 3) * 1024 + k0, Bs + seg * 512);
        }
        __syncthreads();

        short8 af[4][2], bf[4][2];
#pragma unroll
        for (int m = 0; m < 4; ++m) {
            const int row = wr + (m << 4) + lr;
#pragma unroll
            for (int h = 0; h < 2; ++h)
                af[m][h] = ld8(&As[row * 64 + ((((h << 2) + lg) ^ (lr & 7)) << 3)]);
        }
#pragma unroll
        for (int n = 0; n < 4; ++n) {
            const int row = wc + (n << 4) + lr;
#pragma unroll
            for (int h = 0; h < 2; ++h)
                bf[n][h] = ld8(&Bs[row * 64 + ((((h << 2) + lg) ^ (lr & 7)) << 3)]);
        }
#pragma unroll
        for (int m = 0; m < 4; ++m)
#pragma unroll
            for (int n = 0; n < 4; ++n) {
                acc[m][n] = __builtin_amdgcn_mfma_f32_16x16x32_bf16(af[m][0], bf[n][0], acc[m][n], 0, 0, 0);
                acc[m][n] = __builtin_amdgcn_mfma_f32_16x16x32_bf16(af[m][1], bf[n][1], acc[m][n], 0, 0, 0);
            }
    }
}

// q+k+v projections in ONE launch: z = blk>>8 (0=q scaled by log2e/8, 1=k,
// both -> (b,h,L,d); 2 = v -> transposed (b,h,d,L)).
__global__ __launch_bounds__(256) void proj_qkv_kernel(
    const unsigned short* __restrict__ Xq, const unsigned short* __restrict__ Xk,
    const unsigned short* __restrict__ Xv, const unsigned short* __restrict__ D,
    const float* __restrict__ bq, const float* __restrict__ bk, const float* __restrict__ bv,
    unsigned short* __restrict__ Qb, unsigned short* __restrict__ Kb,
    unsigned short* __restrict__ VT)
{
    __shared__ __align__(16) unsigned short As[128 * 64];
    __shared__ __align__(16) unsigned short Bs[128 * 64];

    const int z = blockIdx.x >> 8;
    const int d = blockIdx.x & 255;
    const int y = ((d >> 6) << 3) | (d & 7);
    const int x = (d >> 3) & 7;
    const int row0 = y << 7, col0 = x << 7;

    const unsigned short* Xb = (z == 0) ? Xq : (z == 1) ? Xk : Xv;
    const unsigned short* Wb = D + (size_t)z * 1048576;
    const float* bias = (z == 0) ? bq : (z == 1) ? bk : bv;

    f32x4 acc[4][4];
    gemm_bf16_core(Xb, Wb, row0, col0, As, Bs, acc);

    const int t = threadIdx.x;
    const int lane = t & 63;
    const int wid  = t >> 6;
    const int lr = lane & 15, lg = lane >> 4;
    const int wr = (wid >> 1) << 6, wc = (wid & 1) << 6;

    if (z <= 1) {
        // log2e folded into q so softmax can use exp2 (bias inherits it since
        // the reference biases with the scaled q).
        const float scale = (z == 0) ? 0.125f * 1.44269504088896340736f : 1.0f;
        unsigned short* out = (z == 0) ? Qb : Kb;
#pragma unroll
        for (int n = 0; n < 4; ++n) {
            const int o = col0 + wc + (n << 4) + lr;
            const float bo = bias[o];
            const int h = o >> 6, dd = o & 63;
#pragma unroll
            for (int m = 0; m < 4; ++m) {
                const int ib = row0 + wr + (m << 4) + (lg << 2);
#pragma unroll
                for (int r = 0; r < 4; ++r) {
                    const int i = ib + r;
                    out[(((size_t)((i >> 11) * NH + h)) * L_SEQ + (i & (L_SEQ - 1))) * HD + dd] =
                        f2bf((acc[m][n][r] + bo) * scale);
                }
            }
        }
    } else {
#pragma unroll
        for (int n = 0; n < 4; ++n) {
            const int o = col0 + wc + (n << 4) + lr;
            const float bo = bias[o];
            const int h = o >> 6, dd = o & 63;
#pragma unroll
            for (int m = 0; m < 4; ++m) {
                const int ib = row0 + wr + (m << 4) + (lg << 2);
                const int b = ib >> 11, il = ib & (L_SEQ - 1);
                ushort4 pk;
                pk.x = f2bf(acc[m][n][0] + bo);
                pk.y = f2bf(acc[m][n][1] + bo);
                pk.z = f2bf(acc[m][n][2] + bo);
                pk.w = f2bf(acc[m][n][3] + bo);
                *(ushort4*)&VT[(((size_t)(b * NH + h)) * HD + dd) * L_SEQ + il] = pk;
            }
        }
    }
}

__global__ __launch_bounds__(256) void outproj_kernel(
    const unsigned short* __restrict__ Ob, const unsigned short* __restrict__ Wb,
    const float* __restrict__ bias, float* __restrict__ Yout)
{
    __shared__ __align__(16) unsigned short As[128 * 64];
    __shared__ __align__(16) unsigned short Bs[128 * 64];

    const int d = blockIdx.x;
    const int y = ((d >> 6) << 3) | (d & 7);
    const int x = (d >> 3) & 7;
    const int row0 = y << 7, col0 = x << 7;

    f32x4 acc[4][4];
    gemm_bf16_core(Ob, Wb, row0, col0, As, Bs, acc);

    const int t = threadIdx.x;
    const int lane = t & 63;
    const int wid  = t >> 6;
    const int lr = lane & 15, lg = lane >> 4;
    const int wr = (wid >> 1) << 6, wc = (wid & 1) << 6;

#pragma unroll
    for (int n = 0; n < 4; ++n) {
        const int o = col0 + wc + (n << 4) + lr;
        const float bo = bias[o];
#pragma unroll
        for (int m = 0; m < 4; ++m) {
            const int ib = row0 + wr + (m << 4) + (lg << 2);
#pragma unroll
            for (int r = 0; r < 4; ++r)
                Yout[(size_t)(ib + r) * HDIM + o] = acc[m][n][r] + bo;
        }
    }
}

// stage one 64x64 bf16 K and V tile into LDS via global_load_lds:
// linear LDS dest, inverse-swizzled global source (read side XORs chunk^row&7)
__device__ __forceinline__ void stage_kv(
    const unsigned short* __restrict__ kbase, const unsigned short* __restrict__ vbase,
    int j0, unsigned short (*Ksb)[64], unsigned short (*Vsb)[64], int wid, int lane)
{
    const int r8 = lane >> 3;
    const int gc = ((lane & 7) ^ r8) << 3;
#pragma unroll
    for (int s = 0; s < 2; ++s) {
        const int rw = (wid << 4) + (s << 3);
        gl16(kbase + (size_t)(j0 + rw + r8) * HD + gc, &Ksb[rw][0]);
        gl16(vbase + (size_t)(rw + r8) * L_SEQ + j0 + gc, &Vsb[rw][0]);
    }
}

// Flash attention, causal, skewed relative positional bias (transposed-S).
// 4 waves x 16 q-rows; K/V via global_load_lds double-buffer; exp2 softmax
// (log2e pre-folded into q); wave-uniform mask skip; defer-max (THR=8).
__global__ __launch_bounds__(256, 3) void attn_kernel(
    const unsigned short* __restrict__ Q,
    const unsigned short* __restrict__ Kt,
    const unsigned short* __restrict__ VT,
    const unsigned short* __restrict__ PE,
    unsigned short* __restrict__ O)
{
    __shared__ __align__(16) unsigned short Ks[2][64][64];
    __shared__ __align__(16) unsigned short Vs[2][64][64];
    __shared__ __align__(16) float blds_all[4][64][20];

    const int t    = threadIdx.x;
    const int wid  = t >> 6;
    const int lane = t & 63;
    const int lr   = lane & 15;      // qr
    const int lg   = lane >> 4;
    const int lk   = lg << 3;

    const int p   = blockIdx.x;           // 0..1023
    const int bh  = p & 31;               // XCD = p%8 -> 4 bh per XCD
    const int rb  = 31 - (p >> 5);        // LPT: longest first
    const int i0  = rb << 6;
    const int i0w = i0 + (wid << 4);
    const int nt  = rb + 1;

    const unsigned short* kbase = Kt + (size_t)bh * L_SEQ * HD;
    const unsigned short* vbase = VT + (size_t)bh * HD * L_SEQ;

    float (*blds)[20] = blds_all[wid];

    const unsigned short* qb = Q + ((size_t)bh * L_SEQ + i0w + lr) * HD + lk;
    const short8 aq0 = ld8(qb);
    const short8 aq1 = ld8(qb + 32);

    const int gi    = i0w + lr;
    const int idx0  = ((lg & 1) << 7) + (lr << 2);   // byte index for ds_bpermute
    const int idx1  = idx0 + 64;
    const int selhi = lg >> 1;

    f32x4 oacc[4];
#pragma unroll
    for (int dt = 0; dt < 4; ++dt) oacc[dt] = (f32x4)0.0f;
    float mrun = -__builtin_inff();
    float lrun = 0.0f;

    const int jend = i0w + 15;

    f32x4 pqc = (f32x4)0.0f;
    {
        const unsigned short* pp = PE + (size_t)(2032 - i0w + lr) * HD + lk;
        pqc = __builtin_amdgcn_mfma_f32_16x16x32_bf16(aq0, ld8(pp), pqc, 0, 0, 0);
        pqc = __builtin_amdgcn_mfma_f32_16x16x32_bf16(aq1, ld8(pp + 32), pqc, 0, 0, 0);
    }

    // prologue: stage tile 0 into buffer 0
    stage_kv(kbase, vbase, 0, Ks[0], Vs[0], wid, lane);
    __syncthreads();

    int cur = 0;
    for (int tt = 0; tt < nt; ++tt) {
        const int j0   = tt << 6;
        const bool more = (tt + 1 < nt);

        if (more)
            stage_kv(kbase, vbase, j0 + 64, Ks[cur ^ 1], Vs[cur ^ 1], wid, lane);

        if (j0 <= jend) {
            // ---- QK^T (transposed): K frags from swizzled LDS ----
            f32x4 s2[4];
#pragma unroll
            for (int ct = 0; ct < 4; ++ct) {
                const int row = (ct << 4) + lr;
                const short8 k0 = *(const short8*)&Ks[cur][row][(lg ^ (lr & 7)) << 3];
                const short8 k1 = *(const short8*)&Ks[cur][row][((4 + lg) ^ (lr & 7)) << 3];
                f32x4 a = (f32x4)0.0f;
                a = __builtin_amdgcn_mfma_f32_16x16x32_bf16(k0, aq0, a, 0, 0, 0);
                a = __builtin_amdgcn_mfma_f32_16x16x32_bf16(k1, aq1, a, 0, 0, 0);
                s2[ct] = a;
            }

            // ---- relative positional bias (global PE path) ----
            const int mlo = 2032 + j0 - i0w;
            f32x4 pq[5];
            pq[0] = pqc;
#pragma unroll
            for (int pt = 1; pt < 5; ++pt) {
                f32x4 a = (f32x4)0.0f;
                const unsigned short* pp = PE + (size_t)(mlo + (pt << 4) + lr) * HD + lk;
                a = __builtin_amdgcn_mfma_f32_16x16x32_bf16(aq0, ld8(pp), a, 0, 0, 0);
                a = __builtin_amdgcn_mfma_f32_16x16x32_bf16(aq1, ld8(pp + 32), a, 0, 0, 0);
                pq[pt] = a;
            }
            pqc = pq[4];

            // scatter Pq with skew folded in: blds[kr = pe_c + qw - 15][qw]
#pragma unroll
            for (int r = 0; r < 4; ++r) {
                const int qw = (lg << 2) + r;
                {
                    const int kr = lr + qw - 15;
                    if (kr >= 0) blds[kr][qw] = pq[0][r];
                }
#pragma unroll
                for (int pt = 1; pt < 4; ++pt)
                    blds[(pt << 4) + lr + qw - 15][qw] = pq[pt][r];
                {
                    const int kr = 49 + lr + qw;
                    if (kr < 64) blds[kr][qw] = pq[4][r];
                }
            }

            // bias add; causal mask only on tiles that touch the diagonal
            if (j0 + 63 > i0w) {
#pragma unroll
                for (int ct = 0; ct < 4; ++ct)
#pragma unroll
                    for (int r = 0; r < 4; ++r) {
                        const int krl = (ct << 4) + (lg << 2) + r;
                        const float v = s2[ct][r] + blds[krl][lr];
                        s2[ct][r] = (j0 + krl > gi) ? -__builtin_inff() : v;
                    }
            } else {
#pragma unroll
                for (int ct = 0; ct < 4; ++ct)
#pragma unroll
                    for (int r = 0; r < 4; ++r) {
                        const int krl = (ct << 4) + (lg << 2) + r;
                        s2[ct][r] += blds[krl][lr];
                    }
            }

            // online softmax (exp2 domain): per-lane row; tree + 2 shuffles
            float c0 = fmaxf(fmaxf(s2[0][0], s2[0][1]), fmaxf(s2[0][2], s2[0][3]));
            float c1 = fmaxf(fmaxf(s2[1][0], s2[1][1]), fmaxf(s2[1][2], s2[1][3]));
            float c2 = fmaxf(fmaxf(s2[2][0], s2[2][1]), fmaxf(s2[2][2], s2[2][3]));
            float c3 = fmaxf(fmaxf(s2[3][0], s2[3][1]), fmaxf(s2[3][2], s2[3][3]));
            float vmax = fmaxf(fmaxf(c0, c1), fmaxf(c2, c3));
            vmax = fmaxf(vmax, __shfl_xor(vmax, 16));
            vmax = fmaxf(vmax, __shfl_xor(vmax, 32));
            // defer-max (T13): skip rescale unless some row's max grew > 8
            if (!__all(vmax <= mrun + 8.0f)) {
                const float mnew = fmaxf(mrun, vmax);
                const float sc = __builtin_amdgcn_exp2f(mrun - mnew);
                mrun = mnew;
                lrun *= sc;
#pragma unroll
                for (int dt = 0; dt < 4; ++dt)
#pragma unroll
                    for (int r = 0; r < 4; ++r)
                        oacc[dt][r] *= sc;
            }
#pragma unroll
            for (int ct = 0; ct < 4; ++ct)
#pragma unroll
                for (int r = 0; r < 4; ++r)
                    s2[ct][r] = __builtin_amdgcn_exp2f(s2[ct][r] - mrun);
            float t0 = (s2[0][0] + s2[0][1]) + (s2[0][2] + s2[0][3]);
            float t1 = (s2[1][0] + s2[1][1]) + (s2[1][2] + s2[1][3]);
            float t2 = (s2[2][0] + s2[2][1]) + (s2[2][2] + s2[2][3]);
            float t3 = (s2[3][0] + s2[3][1]) + (s2[3][2] + s2[3][3]);
            float sum = (t0 + t1) + (t2 + t3);
            sum += __shfl_xor(sum, 16);
            sum += __shfl_xor(sum, 32);
            lrun += sum;

            // P -> bf16 B-fragments via cvt_pk + ds_bpermute (proven path)
            unsigned int pkl[4], pkh[4];
#pragma unroll
            for (int ct = 0; ct < 4; ++ct) {
                pkl[ct] = cvtpk(s2[ct][0], s2[ct][1]);
                pkh[ct] = cvtpk(s2[ct][2], s2[ct][3]);
            }
            union { short8 v; int u[4]; } pf0, pf1;
#pragma unroll
            for (int m = 0; m < 4; ++m) {
                const int bidx = (m & 2) ? idx1 : idx0;
                const int a0 = __builtin_amdgcn_ds_bpermute(bidx, (int)((m & 1) ? pkh[0] : pkl[0]));
                const int a1 = __builtin_amdgcn_ds_bpermute(bidx, (int)((m & 1) ? pkh[1] : pkl[1]));
                pf0.u[m] = selhi ? a1 : a0;
                const int b0 = __builtin_amdgcn_ds_bpermute(bidx, (int)((m & 1) ? pkh[2] : pkl[2]));
                const int b1 = __builtin_amdgcn_ds_bpermute(bidx, (int)((m & 1) ? pkh[3] : pkl[3]));
                pf1.u[m] = selhi ? b1 : b0;
            }

            // PV: V frags from swizzled LDS (16x16x32, proven)
#pragma unroll
            for (int dt = 0; dt < 4; ++dt) {
                const int row = (dt << 4) + lr;
                const short8 v0 = *(const short8*)&Vs[cur][row][(lg ^ (lr & 7)) << 3];
                const short8 v1 = *(const short8*)&Vs[cur][row][((4 + lg) ^ (lr & 7)) << 3];
                oacc[dt] = __builtin_amdgcn_mfma_f32_16x16x32_bf16(v0, pf0.v, oacc[dt], 0, 0, 0);
                oacc[dt] = __builtin_amdgcn_mfma_f32_16x16x32_bf16(v1, pf1.v, oacc[dt], 0, 0, 0);
            }
        }

        __syncthreads();
        cur ^= 1;
    }

    // epilogue: normalize, convert to bf16, store 8B per dt
    const float inv = 1.0f / lrun;
    const int b = bh >> 4, h = bh & 15;
#pragma unroll
    for (int dt = 0; dt < 4; ++dt) {
        uint2 u;
        u.x = cvtpk(oacc[dt][0] * inv, oacc[dt][1] * inv);
        u.y = cvtpk(oacc[dt][2] * inv, oacc[dt][3] * inv);
        *(uint2*)&O[((size_t)b * L_SEQ + i0w + lr) * HDIM + (h << 6) + (dt << 4) + (lg << 2)] = u;
    }
}

extern "C" void kernel_launch(void* const* d_in, const int* in_sizes, int n_in,
                              void* d_out, int out_size, void* d_ws, size_t ws_size,
                              hipStream_t stream) {
    (void)in_sizes; (void)n_in; (void)out_size;

    const float* query   = (const float*)d_in[0];
    const float* key_    = (const float*)d_in[1];
    const float* value   = (const float*)d_in[2];
    const float* Wq_w    = (const float*)d_in[3];
    const float* Wq_b    = (const float*)d_in[4];
    const float* Wk_w    = (const float*)d_in[5];
    const float* Wk_b    = (const float*)d_in[6];
    const float* Wv_w    = (const float*)d_in[7];
    const float* Wv_b    = (const float*)d_in[8];
    const float* Wo_w    = (const float*)d_in[9];
    const float* Wo_b    = (const float*)d_in[10];
    const float* pos_emb = (const float*)d_in[11];

    char* ws = (char*)d_ws;
    const size_t MB = 1024 * 1024;
    unsigned short* S1 = (unsigned short*)(ws);                 // 8 MB: q_bf16, later O_bf16
    unsigned short* Qb = (unsigned short*)(ws + 8  * MB);       // 8 MB
    unsigned short* Kb = (unsigned short*)(ws + 16 * MB);       // 8 MB
    unsigned short* Vb = (unsigned short*)(ws + 24 * MB);       // 8 MB: k_bf16
    unsigned short* D  = (unsigned short*)(ws + 32 * MB);       // 8 MB: Wq|Wk|Wv|Wo bf16
    unsigned short* E  = (unsigned short*)(ws + 40 * MB);       // 512 KB pe bf16

    // d_out (16.78 MB) doubles as scratch before the final overwrite:
    // half 0 = v_bf16 input, half 1 = vT (b,h,d,L)
    unsigned short* VSCR = (unsigned short*)d_out;
    unsigned short* VT   = VSCR + 4194304;

    const int npe = (2 * L_SEQ - 1) * HD;
    if (ws_size < (size_t)40 * MB + (size_t)npe * 2) return;

    cvt_a_kernel<<<dim3(2048, 8), 256, 0, stream>>>(query, key_, value,
                                                    Wq_w, Wk_w, Wv_w, Wo_w, pos_emb,
                                                    S1, Vb, VSCR, D, E);
    proj_qkv_kernel<<<768, 256, 0, stream>>>(S1, Vb, VSCR, D, Wq_b, Wk_b, Wv_b,
                                             Qb, Kb, VT);
    attn_kernel<<<1024, 256, 0, stream>>>(Qb, Kb, VT, E, S1);
    outproj_kernel<<<256, 256, 0, stream>>>(S1, D + 3145728, Wo_b, (float*)d_out);
}